// Round 15
// baseline (125.159 us; speedup 1.0000x reference)
//
#include <hip/hip_runtime.h>
#include <stdint.h>

typedef __attribute__((ext_vector_type(8))) short short8;
typedef __attribute__((ext_vector_type(4))) short short4v;
typedef __attribute__((ext_vector_type(4))) float f32x4;
typedef __attribute__((ext_vector_type(16))) float f32x16;

__device__ __forceinline__ short f2bf(float x) {
  union { float f; uint32_t u; } c; c.f = x;
  uint32_t r = (c.u + 0x7FFFu + ((c.u >> 16) & 1u)) >> 16;
  return (short)r;
}
__device__ __forceinline__ float b2f(short s) {
  union { uint32_t u; float f; } c; c.u = ((uint32_t)(uint16_t)s) << 16;
  return c.f;
}
__device__ __forceinline__ uint32_t pack2bf(float lo, float hi) {
  return ((uint32_t)(uint16_t)f2bf(hi) << 16) | (uint32_t)(uint16_t)f2bf(lo);
}

// ============ merged prep: cvt(x) + tcvt(Wqkv) + tcvt(Wout) ============
__global__ __launch_bounds__(256) void prep_kernel(const float* __restrict__ x,
                                                   const float* __restrict__ Wqkv,
                                                   const float* __restrict__ Wout,
                                                   short* __restrict__ xb,
                                                   short* __restrict__ wqkvT,
                                                   short* __restrict__ woutT) {
  __shared__ __align__(16) short tile[32][33];
  const int bid = blockIdx.x;
  if (bid < 2048) {
    const int n4 = (4 * 1024 * 1024) / 4;
    int i = bid * 256 + threadIdx.x;
    for (; i < n4; i += 2048 * 256) {
      float4 v = reinterpret_cast<const float4*>(x)[i];
      short4v o;
      o.x = f2bf(v.x); o.y = f2bf(v.y); o.z = f2bf(v.z); o.w = f2bf(v.w);
      reinterpret_cast<short4v*>(xb)[i] = o;
    }
  } else {
    const float* in;
    short* out;
    int K, N, bx, by;
    if (bid < 2048 + 3072) {
      const int idx = bid - 2048;
      in = Wqkv; out = wqkvT; K = 1024; N = 3072; bx = idx % 96; by = idx / 96;
    } else {
      const int idx = bid - 5120;
      in = Wout; out = woutT; K = 1024; N = 1024; bx = idx % 32; by = idx / 32;
    }
    const int nb = bx * 32, kb = by * 32;
    const int tx = threadIdx.x & 31, ty = threadIdx.x >> 5; // 32 x 8
#pragma unroll
    for (int i = 0; i < 32; i += 8)
      tile[ty + i][tx] = f2bf(in[(size_t)(kb + ty + i) * N + nb + tx]);
    __syncthreads();
#pragma unroll
    for (int i = 0; i < 32; i += 8)
      out[(size_t)(nb + ty + i) * K + kb + tx] = tile[tx][ty + i];
  }
}

// ============ vtrans: qkv[b][kv][2048+c] -> vT[b][c][kv] ============
__global__ __launch_bounds__(256) void vtrans_kernel(const short* __restrict__ qkvb,
                                                     short* __restrict__ vT) {
  __shared__ __align__(16) short tile[64][65];
  const int bid = blockIdx.x;
  const int b = bid / 256;
  const int kv0 = (bid % 16) * 64, c0 = ((bid / 16) % 16) * 64;
  const int tx = threadIdx.x & 15, ty = threadIdx.x >> 4; // 16 x 16
  const short* src = qkvb + (size_t)(b * 1024) * 3072 + 2048;
#pragma unroll
  for (int i = 0; i < 64; i += 16) {
    int r = ty + i;
#pragma unroll
    for (int j = 0; j < 4; ++j)
      tile[r][tx * 4 + j] = src[(size_t)(kv0 + r) * 3072 + c0 + tx * 4 + j];
  }
  __syncthreads();
  short* dst = vT + (size_t)b * 1024 * 1024;
#pragma unroll
  for (int i = 0; i < 64; i += 16) {
    int cc = ty + i;
#pragma unroll
    for (int j = 0; j < 4; ++j)
      dst[(size_t)(c0 + cc) * 1024 + kv0 + tx * 4 + j] = tile[tx * 4 + j][cc];
  }
}

// ---------------- bf16 MFMA GEMM: C[M][N] = A[M][K] * Bt[N][K]^T (128^2) ----------------
template <int OUT_BF16>
__global__ __launch_bounds__(256) void gemm_kernel(const short* __restrict__ A,
                                                   const short* __restrict__ Bt,
                                                   void* __restrict__ Cout,
                                                   int K, int ldc) {
  __shared__ __align__(16) short Al[2][128 * 32];
  __shared__ __align__(16) short Bl[2][128 * 32];
  const int t = threadIdx.x;
  const int lane = t & 63, w = t >> 6;
  const int wr = w >> 1, wc = w & 1;
  const int g = lane >> 4, c16 = lane & 15;
  const int row0 = blockIdx.y * 128, col0 = blockIdx.x * 128;

  f32x4 acc[4][4];
#pragma unroll
  for (int m = 0; m < 4; ++m)
#pragma unroll
    for (int n = 0; n < 4; ++n) {
      f32x4 z = {0.0f, 0.0f, 0.0f, 0.0f};
      acc[m][n] = z;
    }

  auto stage = [&](int buf, int kt) {
    const int k0 = kt * 32;
#pragma unroll
    for (int i = 0; i < 2; ++i) {
      const int qb = i * 256 + (t & 192); // wave-uniform chunk base
      const int q = qb + lane;
      const int r = q >> 2;
      const int c = (q & 3) ^ ((r >> 1) & 3);
      const short* ga = A + (size_t)(row0 + r) * K + k0 + c * 8;
      const short* gb = Bt + (size_t)(col0 + r) * K + k0 + c * 8;
      __builtin_amdgcn_global_load_lds((const __attribute__((address_space(1))) void*)ga,
                                       (__attribute__((address_space(3))) void*)&Al[buf][qb * 8],
                                       16, 0, 0);
      __builtin_amdgcn_global_load_lds((const __attribute__((address_space(1))) void*)gb,
                                       (__attribute__((address_space(3))) void*)&Bl[buf][qb * 8],
                                       16, 0, 0);
    }
  };

  stage(0, 0);
  __syncthreads();
  const int NK = K >> 5;
  int cur = 0;
  const int rA0 = wr * 64 + c16;
  const int rB0 = wc * 64 + c16;
  for (int kt = 0; kt < NK; ++kt) {
    if (kt + 1 < NK) stage(cur ^ 1, kt + 1);
    short8 aF[4], bF[4];
#pragma unroll
    for (int m = 0; m < 4; ++m) {
      const int r = rA0 + m * 16;
      const int c = g ^ ((r >> 1) & 3);
      aF[m] = *reinterpret_cast<const short8*>(&Al[cur][r * 32 + c * 8]);
    }
#pragma unroll
    for (int n = 0; n < 4; ++n) {
      const int r = rB0 + n * 16;
      const int c = g ^ ((r >> 1) & 3);
      bF[n] = *reinterpret_cast<const short8*>(&Bl[cur][r * 32 + c * 8]);
    }
#pragma unroll
    for (int m = 0; m < 4; ++m)
#pragma unroll
      for (int n = 0; n < 4; ++n)
        acc[m][n] = __builtin_amdgcn_mfma_f32_16x16x32_bf16(aF[m], bF[n], acc[m][n], 0, 0, 0);
    __syncthreads();
    cur ^= 1;
  }

  const int er = row0 + wr * 64 + g * 4;
  const int ec = col0 + wc * 64 + c16;
#pragma unroll
  for (int m = 0; m < 4; ++m)
#pragma unroll
    for (int n = 0; n < 4; ++n)
#pragma unroll
      for (int j = 0; j < 4; ++j) {
        const size_t off = (size_t)(er + m * 16 + j) * ldc + ec + n * 16;
        if (OUT_BF16)
          ((short*)Cout)[off] = f2bf(acc[m][n][j]);
        else
          ((float*)Cout)[off] = acc[m][n][j];
      }
}

// ------------- bf16 MFMA GEMM: 128x64 tile (for small-N gemm2: 2x grid) -------------
template <int OUT_BF16>
__global__ __launch_bounds__(256) void gemm64_kernel(const short* __restrict__ A,
                                                     const short* __restrict__ Bt,
                                                     void* __restrict__ Cout,
                                                     int K, int ldc) {
  __shared__ __align__(16) short Al[2][128 * 32];
  __shared__ __align__(16) short Bl[2][64 * 32];
  const int t = threadIdx.x;
  const int lane = t & 63, w = t >> 6;
  const int wr = w >> 1, wc = w & 1;
  const int g = lane >> 4, c16 = lane & 15;
  const int row0 = blockIdx.y * 128, col0 = blockIdx.x * 64;

  f32x4 acc[4][2];
#pragma unroll
  for (int m = 0; m < 4; ++m)
#pragma unroll
    for (int n = 0; n < 2; ++n) {
      f32x4 z = {0.0f, 0.0f, 0.0f, 0.0f};
      acc[m][n] = z;
    }

  auto stage = [&](int buf, int kt) {
    const int k0 = kt * 32;
#pragma unroll
    for (int i = 0; i < 2; ++i) { // A: 512 chunks over 2 iters
      const int qb = i * 256 + (t & 192);
      const int q = qb + lane;
      const int r = q >> 2;
      const int c = (q & 3) ^ ((r >> 1) & 3);
      const short* ga = A + (size_t)(row0 + r) * K + k0 + c * 8;
      __builtin_amdgcn_global_load_lds((const __attribute__((address_space(1))) void*)ga,
                                       (__attribute__((address_space(3))) void*)&Al[buf][qb * 8],
                                       16, 0, 0);
    }
    { // B: 256 chunks in 1 iter
      const int qb = (t & 192);
      const int q = qb + lane;
      const int r = q >> 2;
      const int c = (q & 3) ^ ((r >> 1) & 3);
      const short* gb = Bt + (size_t)(col0 + r) * K + k0 + c * 8;
      __builtin_amdgcn_global_load_lds((const __attribute__((address_space(1))) void*)gb,
                                       (__attribute__((address_space(3))) void*)&Bl[buf][qb * 8],
                                       16, 0, 0);
    }
  };

  stage(0, 0);
  __syncthreads();
  const int NK = K >> 5;
  int cur = 0;
  const int rA0 = wr * 64 + c16;
  const int rB0 = wc * 32 + c16;
  for (int kt = 0; kt < NK; ++kt) {
    if (kt + 1 < NK) stage(cur ^ 1, kt + 1);
    short8 aF[4], bF[2];
#pragma unroll
    for (int m = 0; m < 4; ++m) {
      const int r = rA0 + m * 16;
      const int c = g ^ ((r >> 1) & 3);
      aF[m] = *reinterpret_cast<const short8*>(&Al[cur][r * 32 + c * 8]);
    }
#pragma unroll
    for (int n = 0; n < 2; ++n) {
      const int r = rB0 + n * 16;
      const int c = g ^ ((r >> 1) & 3);
      bF[n] = *reinterpret_cast<const short8*>(&Bl[cur][r * 32 + c * 8]);
    }
#pragma unroll
    for (int m = 0; m < 4; ++m)
#pragma unroll
      for (int n = 0; n < 2; ++n)
        acc[m][n] = __builtin_amdgcn_mfma_f32_16x16x32_bf16(aF[m], bF[n], acc[m][n], 0, 0, 0);
    __syncthreads();
    cur ^= 1;
  }

  const int er = row0 + wr * 64 + g * 4;
  const int ec = col0 + wc * 32 + c16;
#pragma unroll
  for (int m = 0; m < 4; ++m)
#pragma unroll
    for (int n = 0; n < 2; ++n)
#pragma unroll
      for (int j = 0; j < 4; ++j) {
        const size_t off = (size_t)(er + m * 16 + j) * ldc + ec + n * 16;
        if (OUT_BF16)
          ((short*)Cout)[off] = f2bf(acc[m][n][j]);
        else
          ((float*)Cout)[off] = acc[m][n][j];
      }
}

// ---------------- fused causal attention: 32x32 MFMA, kv-halved waves ----------------
// r14 structure + ILP fix: QK split into TWO independent 4-deep MFMA chains
// (was one 8-deep serial chain), P-exchange shuffles halved 8 -> 4 (each
// shfl_xor carries a different word per lh half). Everything else unchanged.
struct AttnSmem {
  union {
    struct {
      short Kl[2][64 * 128];
      short Vl[2][128 * 64];
      float kp[2][64];
    } s;
    float mg[2 * 64 * 66]; // merge buffer (33.8KB), reused after main loop
  };
};

__global__ __launch_bounds__(256) void attn_kernel(const short* __restrict__ qkvb,
                                                   const short* __restrict__ vT,
                                                   const float* __restrict__ head_scales,
                                                   const float* __restrict__ hdirs,
                                                   short* __restrict__ attnb) {
  __shared__ __align__(16) AttnSmem sm;

  const int bid = blockIdx.x;                       // 0..511
  const int bh = (bid & 7) * 4 + ((bid >> 3) & 3);  // 4 bh per XCD
  const int r2 = bid >> 5;                          // 0..15
  const int qt = (bid < 256) ? (15 - r2) : (r2 - 8); // balanced CU pairing
  const int b = bh >> 3, h = bh & 7;
  const int t = threadIdx.x, lane = t & 63, w = t >> 6;
  const int hk = w >> 1, hq = w & 1;
  const int g = lane >> 4, c16 = lane & 15;   // staging roles
  const int l31 = lane & 31, lh = lane >> 5;  // compute roles
  const int q0w = qt * 64 + hq * 32;
  const int q_abs = q0w + l31; // this lane's q row

  const short* qbase = qkvb + (size_t)(b * 1024) * 3072 + h * 128;
  const short* kbase = qbase + 1024;
  const short* vtb = vT + (size_t)bh * 128 * 1024;

  const float LOG2E = 1.44269504088896f;
  const float scale2 = 0.08838834764831845f * 1.44269504088896f; // /sqrt(128)*log2e
  const float d0 = hdirs[h * 3], d1 = hdirs[h * 3 + 1], d2 = hdirs[h * 3 + 2];

  // Q fragments (B-operand of 32x32x16): n = l31 = q, k = lh*8 within 16-window
  short8 aQ[8];
  float hqp;
  {
    const short* qr = qbase + (size_t)q_abs * 3072;
#pragma unroll
    for (int dd = 0; dd < 8; ++dd)
      aQ[dd] = *reinterpret_cast<const short8*>(qr + dd * 16 + lh * 8);
    const float hs = head_scales[h];
    hqp = hs * LOG2E * (b2f(qr[0]) * d0 + b2f(qr[1]) * d1 + b2f(qr[2]) * d2);
  }

  float m_s = -1e30f, l_s = 0.0f; // per q (= l31), replicated across lh
  f32x16 accO[4];
#pragma unroll
  for (int dc = 0; dc < 4; ++dc) {
    f32x16 z = {0, 0, 0, 0, 0, 0, 0, 0, 0, 0, 0, 0, 0, 0, 0, 0};
    accO[dc] = z;
  }

  auto stageKV = [&](int buf, int kvt) {
    const int kv0 = kvt * 64;
#pragma unroll
    for (int i = 0; i < 4; ++i) {
      const int s = w * 4 + i;
      {
        const int r = s * 4 + g;             // kv row
        const int c = c16 ^ (r & 15);        // global 16B chunk (16/row), r&15 swizzle
        const short* ga = kbase + (size_t)(kv0 + r) * 3072 + c * 8;
        __builtin_amdgcn_global_load_lds((const __attribute__((address_space(1))) void*)ga,
                                         (__attribute__((address_space(3))) void*)&sm.s.Kl[buf][s * 512],
                                         16, 0, 0);
      }
      {
        const int r = s * 8 + (lane >> 3);   // d row
        const int c = (lane & 7) ^ (r & 7);  // global 16B chunk (8/row)
        const short* ga = vtb + (size_t)r * 1024 + kv0 + c * 8;
        __builtin_amdgcn_global_load_lds((const __attribute__((address_space(1))) void*)ga,
                                         (__attribute__((address_space(3))) void*)&sm.s.Vl[buf][s * 512],
                                         16, 0, 0);
      }
    }
    if (lane < 16) {
      const short* kr = kbase + (size_t)(kv0 + w * 16 + lane) * 3072;
      sm.s.kp[buf][w * 16 + lane] = b2f(kr[0]) * d0 + b2f(kr[1]) * d1 + b2f(kr[2]) * d2;
    }
  };

  const int nkv = qt + 1;
  stageKV(0, 0);
  __syncthreads();
  int cur = 0;
  for (int kvt = 0; kvt < nkv; ++kvt) {
    const int kv0 = kvt * 64;
    if (kvt + 1 < nkv) stageKV(cur ^ 1, kvt + 1); // prefetch overlaps compute
    const short* Kc = sm.s.Kl[cur];
    const short* Vc = sm.s.Vl[cur];
    const float* kpc = sm.s.kp[cur];
    const bool active = !(kvt == qt && hk == 1 && hq == 0); // fully-masked wave skips

    if (active) {
      // ---- QK^T (swapped): TWO independent 4-deep MFMA chains ----
      f32x16 s4a = {0, 0, 0, 0, 0, 0, 0, 0, 0, 0, 0, 0, 0, 0, 0, 0};
      f32x16 s4b = {0, 0, 0, 0, 0, 0, 0, 0, 0, 0, 0, 0, 0, 0, 0, 0};
      const int kr = hk * 32 + l31;
      const int rx = kr & 15;
#pragma unroll
      for (int dd = 0; dd < 4; ++dd) {
        short8 aK0 = *reinterpret_cast<const short8*>(&Kc[kr * 128 + (((dd << 1) | lh) ^ rx) * 8]);
        short8 aK1 = *reinterpret_cast<const short8*>(&Kc[kr * 128 + ((((dd + 4) << 1) | lh) ^ rx) * 8]);
        s4a = __builtin_amdgcn_mfma_f32_32x32x16_bf16(aK0, aQ[dd], s4a, 0, 0, 0);
        s4b = __builtin_amdgcn_mfma_f32_32x32x16_bf16(aK1, aQ[dd + 4], s4b, 0, 0, 0);
      }
      // ---- bias + causal mask (lane holds 16 kv-rows for q = l31) ----
      float p[16];
#pragma unroll
      for (int reg = 0; reg < 16; ++reg) {
        const int row = (reg & 3) + 8 * (reg >> 2) + 4 * lh;
        const int kva = kv0 + hk * 32 + row;
        const float v = (s4a[reg] + s4b[reg]) * scale2 + hqp * kpc[hk * 32 + row];
        p[reg] = (kva <= q_abs) ? v : -1e30f;
      }
      // ---- row max: 15-op tree + 1 shfl_xor(32) ----
      float mx;
      {
        float a0 = fmaxf(fmaxf(p[0], p[1]), fmaxf(p[2], p[3]));
        float a1 = fmaxf(fmaxf(p[4], p[5]), fmaxf(p[6], p[7]));
        float a2 = fmaxf(fmaxf(p[8], p[9]), fmaxf(p[10], p[11]));
        float a3 = fmaxf(fmaxf(p[12], p[13]), fmaxf(p[14], p[15]));
        mx = fmaxf(fmaxf(a0, a1), fmaxf(a2, a3));
        mx = fmaxf(mx, __shfl_xor(mx, 32, 64));
      }
      // ---- defer-max (THR = 8 nats) ----
      if (__any(mx - m_s > 11.54f)) {
        const float mn = fmaxf(m_s, mx);
        const float alpha = exp2f(m_s - mn);
        m_s = mn;
        l_s *= alpha;
        float aR[16];
#pragma unroll
        for (int reg = 0; reg < 16; ++reg)
          aR[reg] = __shfl(alpha, (reg & 3) + 8 * (reg >> 2) + 4 * lh, 64);
#pragma unroll
        for (int dc = 0; dc < 4; ++dc)
#pragma unroll
          for (int reg = 0; reg < 16; ++reg) accO[dc][reg] *= aR[reg];
      }
      // ---- exp2 + row sum ----
      float sum = 0.0f;
#pragma unroll
      for (int reg = 0; reg < 16; ++reg) {
        p[reg] = exp2f(p[reg] - m_s);
        sum += p[reg];
      }
      sum += __shfl_xor(sum, 32, 64);
      l_s += sum;
      // ---- pack to bf16 pairs; 4-shfl half-exchange for PV A-operand ----
      uint32_t pk[8];
#pragma unroll
      for (int i = 0; i < 8; ++i) pk[i] = pack2bf(p[2 * i], p[2 * i + 1]);
      const uint32_t r0 = (uint32_t)__shfl_xor((int)(lh ? pk[0] : pk[2]), 32, 64);
      const uint32_t r1 = (uint32_t)__shfl_xor((int)(lh ? pk[1] : pk[3]), 32, 64);
      const uint32_t r2x = (uint32_t)__shfl_xor((int)(lh ? pk[4] : pk[6]), 32, 64);
      const uint32_t r3x = (uint32_t)__shfl_xor((int)(lh ? pk[5] : pk[7]), 32, 64);
      union { uint32_t d[4]; short8 s; } A1, A2;
      A1.d[0] = lh ? r0 : pk[0];
      A1.d[1] = lh ? r1 : pk[1];
      A1.d[2] = lh ? pk[2] : r0;
      A1.d[3] = lh ? pk[3] : r1;
      A2.d[0] = lh ? r2x : pk[4];
      A2.d[1] = lh ? r3x : pk[5];
      A2.d[2] = lh ? pk[6] : r2x;
      A2.d[3] = lh ? pk[7] : r3x;
      // ---- PV: D[q][d], A = P-frag, B = V^T rows d, kv window of half hk ----
#pragma unroll
      for (int dc = 0; dc < 4; ++dc) {
        const int vr = dc * 32 + l31;
        const int vx = vr & 7;
        short8 bV0 = *reinterpret_cast<const short8*>(&Vc[vr * 64 + (((hk << 2) | lh) ^ vx) * 8]);
        short8 bV1 = *reinterpret_cast<const short8*>(&Vc[vr * 64 + (((hk << 2) | 2 | lh) ^ vx) * 8]);
        accO[dc] = __builtin_amdgcn_mfma_f32_32x32x16_bf16(A1.s, bV0, accO[dc], 0, 0, 0);
        accO[dc] = __builtin_amdgcn_mfma_f32_32x32x16_bf16(A2.s, bV1, accO[dc], 0, 0, 0);
      }
    }
    __syncthreads(); // next buffer staged + all waves done reading cur
    cur ^= 1;
  }

  // ---- flash-merge hk halves (same q, same layout) via LDS reuse ----
  const int base = (hq * 64 + lane) * 66;
  if (hk == 1) {
    sm.mg[base] = m_s;
    sm.mg[base + 1] = l_s;
#pragma unroll
    for (int dc = 0; dc < 4; ++dc)
#pragma unroll
      for (int reg = 0; reg < 16; ++reg) sm.mg[base + 2 + dc * 16 + reg] = accO[dc][reg];
  }
  __syncthreads();
  if (hk == 0) {
    const float m1 = sm.mg[base], l1 = sm.mg[base + 1];
    const float mn = fmaxf(m_s, m1);
    const float a0 = exp2f(m_s - mn), a1 = exp2f(m1 - mn);
    const float linv = 1.0f / (l_s * a0 + l1 * a1);
    const float f0 = a0 * linv, f1 = a1 * linv;
    float fR0[16], fR1[16];
#pragma unroll
    for (int reg = 0; reg < 16; ++reg) {
      const int row = (reg & 3) + 8 * (reg >> 2) + 4 * lh;
      fR0[reg] = __shfl(f0, row, 64);
      fR1[reg] = __shfl(f1, row, 64);
    }
#pragma unroll
    for (int dc = 0; dc < 4; ++dc)
#pragma unroll
      for (int reg = 0; reg < 16; ++reg) {
        const int row = (reg & 3) + 8 * (reg >> 2) + 4 * lh;
        const float o = accO[dc][reg] * fR0[reg] + sm.mg[base + 2 + dc * 16 + reg] * fR1[reg];
        attnb[(size_t)(b * 1024 + q0w + row) * 1024 + h * 128 + dc * 32 + l31] = f2bf(o);
      }
  }
}

extern "C" void kernel_launch(void* const* d_in, const int* in_sizes, int n_in,
                              void* d_out, int out_size, void* d_ws, size_t ws_size,
                              hipStream_t stream) {
  const float* x = (const float*)d_in[0];
  const float* Wqkv = (const float*)d_in[1];
  const float* Wout = (const float*)d_in[2];
  const float* hscale = (const float*)d_in[3];
  const float* hdirs = (const float*)d_in[4];
  float* out = (float*)d_out;

  char* ws = (char*)d_ws;
  short* xb = (short*)(ws);                                  // 8 MB (dead after gemm1)
  short* wqkvT = (short*)(ws + (size_t)8 * 1024 * 1024);     // 6 MB
  short* woutT = (short*)(ws + (size_t)14 * 1024 * 1024);    // 2 MB
  short* qkvb = (short*)(ws + (size_t)16 * 1024 * 1024);     // 24 MB
  short* vT = (short*)(ws + (size_t)40 * 1024 * 1024);       // 8 MB
  short* attnb = (short*)(ws + (size_t)48 * 1024 * 1024);    // 8 MB

  prep_kernel<<<6144, 256, 0, stream>>>(x, Wqkv, Wout, xb, wqkvT, woutT);
  gemm_kernel<1><<<dim3(24, 32), 256, 0, stream>>>(xb, wqkvT, (void*)qkvb, 1024, 3072);
  vtrans_kernel<<<1024, 256, 0, stream>>>(qkvb, vT);
  attn_kernel<<<512, 256, 0, stream>>>(qkvb, vT, hscale, hdirs, attnb);
  gemm64_kernel<0><<<dim3(16, 32), 256, 0, stream>>>(attnb, woutT, out, 1024, 1024);
}

// Round 16
// 108.867 us; speedup vs baseline: 1.1497x; 1.1497x over previous
//
#include <hip/hip_runtime.h>
#include <stdint.h>

typedef __attribute__((ext_vector_type(8))) short short8;
typedef __attribute__((ext_vector_type(4))) short short4v;
typedef __attribute__((ext_vector_type(4))) float f32x4;

__device__ __forceinline__ short f2bf(float x) {
  union { float f; uint32_t u; } c; c.f = x;
  uint32_t r = (c.u + 0x7FFFu + ((c.u >> 16) & 1u)) >> 16;
  return (short)r;
}
__device__ __forceinline__ float b2f(short s) {
  union { uint32_t u; float f; } c; c.u = ((uint32_t)(uint16_t)s) << 16;
  return c.f;
}
__device__ __forceinline__ uint32_t pack2bf(float lo, float hi) {
  return ((uint32_t)(uint16_t)f2bf(hi) << 16) | (uint32_t)(uint16_t)f2bf(lo);
}

// ============ merged prep: cvt(x) + tcvt(Wqkv) + tcvt(Wout) ============
__global__ __launch_bounds__(256) void prep_kernel(const float* __restrict__ x,
                                                   const float* __restrict__ Wqkv,
                                                   const float* __restrict__ Wout,
                                                   short* __restrict__ xb,
                                                   short* __restrict__ wqkvT,
                                                   short* __restrict__ woutT) {
  __shared__ __align__(16) short tile[32][33];
  const int bid = blockIdx.x;
  if (bid < 2048) {
    const int n4 = (4 * 1024 * 1024) / 4;
    int i = bid * 256 + threadIdx.x;
    for (; i < n4; i += 2048 * 256) {
      float4 v = reinterpret_cast<const float4*>(x)[i];
      short4v o;
      o.x = f2bf(v.x); o.y = f2bf(v.y); o.z = f2bf(v.z); o.w = f2bf(v.w);
      reinterpret_cast<short4v*>(xb)[i] = o;
    }
  } else {
    const float* in;
    short* out;
    int K, N, bx, by;
    if (bid < 2048 + 3072) {
      const int idx = bid - 2048;
      in = Wqkv; out = wqkvT; K = 1024; N = 3072; bx = idx % 96; by = idx / 96;
    } else {
      const int idx = bid - 5120;
      in = Wout; out = woutT; K = 1024; N = 1024; bx = idx % 32; by = idx / 32;
    }
    const int nb = bx * 32, kb = by * 32;
    const int tx = threadIdx.x & 31, ty = threadIdx.x >> 5; // 32 x 8
#pragma unroll
    for (int i = 0; i < 32; i += 8)
      tile[ty + i][tx] = f2bf(in[(size_t)(kb + ty + i) * N + nb + tx]);
    __syncthreads();
#pragma unroll
    for (int i = 0; i < 32; i += 8)
      out[(size_t)(nb + ty + i) * K + kb + tx] = tile[tx][ty + i];
  }
}

// ============ vtrans: qkv[b][kv][2048+c] -> vT[b][c][kv] ============
__global__ __launch_bounds__(256) void vtrans_kernel(const short* __restrict__ qkvb,
                                                     short* __restrict__ vT) {
  __shared__ __align__(16) short tile[64][65];
  const int bid = blockIdx.x;
  const int b = bid / 256;
  const int kv0 = (bid % 16) * 64, c0 = ((bid / 16) % 16) * 64;
  const int tx = threadIdx.x & 15, ty = threadIdx.x >> 4; // 16 x 16
  const short* src = qkvb + (size_t)(b * 1024) * 3072 + 2048;
#pragma unroll
  for (int i = 0; i < 64; i += 16) {
    int r = ty + i;
#pragma unroll
    for (int j = 0; j < 4; ++j)
      tile[r][tx * 4 + j] = src[(size_t)(kv0 + r) * 3072 + c0 + tx * 4 + j];
  }
  __syncthreads();
  short* dst = vT + (size_t)b * 1024 * 1024;
#pragma unroll
  for (int i = 0; i < 64; i += 16) {
    int cc = ty + i;
#pragma unroll
    for (int j = 0; j < 4; ++j)
      dst[(size_t)(c0 + cc) * 1024 + kv0 + tx * 4 + j] = tile[tx * 4 + j][cc];
  }
}

// ---------------- bf16 MFMA GEMM: C[M][N] = A[M][K] * Bt[N][K]^T (128^2) ----------------
template <int OUT_BF16>
__global__ __launch_bounds__(256) void gemm_kernel(const short* __restrict__ A,
                                                   const short* __restrict__ Bt,
                                                   void* __restrict__ Cout,
                                                   int K, int ldc) {
  __shared__ __align__(16) short Al[2][128 * 32];
  __shared__ __align__(16) short Bl[2][128 * 32];
  const int t = threadIdx.x;
  const int lane = t & 63, w = t >> 6;
  const int wr = w >> 1, wc = w & 1;
  const int g = lane >> 4, c16 = lane & 15;
  const int row0 = blockIdx.y * 128, col0 = blockIdx.x * 128;

  f32x4 acc[4][4];
#pragma unroll
  for (int m = 0; m < 4; ++m)
#pragma unroll
    for (int n = 0; n < 4; ++n) {
      f32x4 z = {0.0f, 0.0f, 0.0f, 0.0f};
      acc[m][n] = z;
    }

  auto stage = [&](int buf, int kt) {
    const int k0 = kt * 32;
#pragma unroll
    for (int i = 0; i < 2; ++i) {
      const int qb = i * 256 + (t & 192); // wave-uniform chunk base
      const int q = qb + lane;
      const int r = q >> 2;
      const int c = (q & 3) ^ ((r >> 1) & 3);
      const short* ga = A + (size_t)(row0 + r) * K + k0 + c * 8;
      const short* gb = Bt + (size_t)(col0 + r) * K + k0 + c * 8;
      __builtin_amdgcn_global_load_lds((const __attribute__((address_space(1))) void*)ga,
                                       (__attribute__((address_space(3))) void*)&Al[buf][qb * 8],
                                       16, 0, 0);
      __builtin_amdgcn_global_load_lds((const __attribute__((address_space(1))) void*)gb,
                                       (__attribute__((address_space(3))) void*)&Bl[buf][qb * 8],
                                       16, 0, 0);
    }
  };

  stage(0, 0);
  __syncthreads();
  const int NK = K >> 5;
  int cur = 0;
  const int rA0 = wr * 64 + c16;
  const int rB0 = wc * 64 + c16;
  for (int kt = 0; kt < NK; ++kt) {
    if (kt + 1 < NK) stage(cur ^ 1, kt + 1);
    short8 aF[4], bF[4];
#pragma unroll
    for (int m = 0; m < 4; ++m) {
      const int r = rA0 + m * 16;
      const int c = g ^ ((r >> 1) & 3);
      aF[m] = *reinterpret_cast<const short8*>(&Al[cur][r * 32 + c * 8]);
    }
#pragma unroll
    for (int n = 0; n < 4; ++n) {
      const int r = rB0 + n * 16;
      const int c = g ^ ((r >> 1) & 3);
      bF[n] = *reinterpret_cast<const short8*>(&Bl[cur][r * 32 + c * 8]);
    }
#pragma unroll
    for (int m = 0; m < 4; ++m)
#pragma unroll
      for (int n = 0; n < 4; ++n)
        acc[m][n] = __builtin_amdgcn_mfma_f32_16x16x32_bf16(aF[m], bF[n], acc[m][n], 0, 0, 0);
    __syncthreads();
    cur ^= 1;
  }

  const int er = row0 + wr * 64 + g * 4;
  const int ec = col0 + wc * 64 + c16;
#pragma unroll
  for (int m = 0; m < 4; ++m)
#pragma unroll
    for (int n = 0; n < 4; ++n)
#pragma unroll
      for (int j = 0; j < 4; ++j) {
        const size_t off = (size_t)(er + m * 16 + j) * ldc + ec + n * 16;
        if (OUT_BF16)
          ((short*)Cout)[off] = f2bf(acc[m][n][j]);
        else
          ((float*)Cout)[off] = acc[m][n][j];
      }
}

// ------------- bf16 MFMA GEMM: 128x64 tile (for small-N gemm2: 2x grid) -------------
template <int OUT_BF16>
__global__ __launch_bounds__(256) void gemm64_kernel(const short* __restrict__ A,
                                                     const short* __restrict__ Bt,
                                                     void* __restrict__ Cout,
                                                     int K, int ldc) {
  __shared__ __align__(16) short Al[2][128 * 32];
  __shared__ __align__(16) short Bl[2][64 * 32];
  const int t = threadIdx.x;
  const int lane = t & 63, w = t >> 6;
  const int wr = w >> 1, wc = w & 1;
  const int g = lane >> 4, c16 = lane & 15;
  const int row0 = blockIdx.y * 128, col0 = blockIdx.x * 64;

  f32x4 acc[4][2];
#pragma unroll
  for (int m = 0; m < 4; ++m)
#pragma unroll
    for (int n = 0; n < 2; ++n) {
      f32x4 z = {0.0f, 0.0f, 0.0f, 0.0f};
      acc[m][n] = z;
    }

  auto stage = [&](int buf, int kt) {
    const int k0 = kt * 32;
#pragma unroll
    for (int i = 0; i < 2; ++i) { // A: 512 chunks over 2 iters
      const int qb = i * 256 + (t & 192);
      const int q = qb + lane;
      const int r = q >> 2;
      const int c = (q & 3) ^ ((r >> 1) & 3);
      const short* ga = A + (size_t)(row0 + r) * K + k0 + c * 8;
      __builtin_amdgcn_global_load_lds((const __attribute__((address_space(1))) void*)ga,
                                       (__attribute__((address_space(3))) void*)&Al[buf][qb * 8],
                                       16, 0, 0);
    }
    { // B: 256 chunks in 1 iter
      const int qb = (t & 192);
      const int q = qb + lane;
      const int r = q >> 2;
      const int c = (q & 3) ^ ((r >> 1) & 3);
      const short* gb = Bt + (size_t)(col0 + r) * K + k0 + c * 8;
      __builtin_amdgcn_global_load_lds((const __attribute__((address_space(1))) void*)gb,
                                       (__attribute__((address_space(3))) void*)&Bl[buf][qb * 8],
                                       16, 0, 0);
    }
  };

  stage(0, 0);
  __syncthreads();
  const int NK = K >> 5;
  int cur = 0;
  const int rA0 = wr * 64 + c16;
  const int rB0 = wc * 32 + c16;
  for (int kt = 0; kt < NK; ++kt) {
    if (kt + 1 < NK) stage(cur ^ 1, kt + 1);
    short8 aF[4], bF[2];
#pragma unroll
    for (int m = 0; m < 4; ++m) {
      const int r = rA0 + m * 16;
      const int c = g ^ ((r >> 1) & 3);
      aF[m] = *reinterpret_cast<const short8*>(&Al[cur][r * 32 + c * 8]);
    }
#pragma unroll
    for (int n = 0; n < 2; ++n) {
      const int r = rB0 + n * 16;
      const int c = g ^ ((r >> 1) & 3);
      bF[n] = *reinterpret_cast<const short8*>(&Bl[cur][r * 32 + c * 8]);
    }
#pragma unroll
    for (int m = 0; m < 4; ++m)
#pragma unroll
      for (int n = 0; n < 2; ++n)
        acc[m][n] = __builtin_amdgcn_mfma_f32_16x16x32_bf16(aF[m], bF[n], acc[m][n], 0, 0, 0);
    __syncthreads();
    cur ^= 1;
  }

  const int er = row0 + wr * 64 + g * 4;
  const int ec = col0 + wc * 32 + c16;
#pragma unroll
  for (int m = 0; m < 4; ++m)
#pragma unroll
    for (int n = 0; n < 2; ++n)
#pragma unroll
      for (int j = 0; j < 4; ++j) {
        const size_t off = (size_t)(er + m * 16 + j) * ldc + ec + n * 16;
        if (OUT_BF16)
          ((short*)Cout)[off] = f2bf(acc[m][n][j]);
        else
          ((float*)Cout)[off] = acc[m][n][j];
      }
}

// ---------------- fused causal attention with trigram geo bias ----------------
// r13 structure (best measured: 41.4us attn / 110.3 total): swapped-QK^T 16x16,
// in-register softmax, K+V double-buffered, one barrier/tile, inline kproj.
// NEW: mask only on diagonal tile; diagonal wave-skip (nmax=w+1) drops dead
// MFMA chains / exp2 / shuffles / PV-half for fully-masked n-blocks.
__global__ __launch_bounds__(256) void attn_kernel(const short* __restrict__ qkvb,
                                                   const short* __restrict__ vT,
                                                   const float* __restrict__ head_scales,
                                                   const float* __restrict__ hdirs,
                                                   short* __restrict__ attnb) {
  __shared__ __align__(16) short Kl[2][64 * 128];
  __shared__ __align__(16) short Vl[2][128 * 64];
  __shared__ float kp_lds[2][64];

  const int bid = blockIdx.x;                       // 0..511
  const int bh = (bid & 7) * 4 + ((bid >> 3) & 3);  // 4 bh per XCD
  const int r2 = bid >> 5;                          // 0..15
  const int qt = (bid < 256) ? (15 - r2) : (r2 - 8); // balanced CU pairing
  const int b = bh >> 3, h = bh & 7;
  const int t = threadIdx.x, lane = t & 63, w = t >> 6;
  const int g = lane >> 4, c16 = lane & 15;
  const int q0w = qt * 64 + w * 16;
  const int q_abs = q0w + c16; // this lane's q row

  const short* qbase = qkvb + (size_t)(b * 1024) * 3072 + h * 128;
  const short* kbase = qbase + 1024;
  const short* vtb = vT + (size_t)bh * 128 * 1024;

  const float LOG2E = 1.44269504088896f;
  const float scale2 = 0.08838834764831845f * 1.44269504088896f; // /sqrt(128)*log2e
  const float d0 = hdirs[h * 3], d1 = hdirs[h * 3 + 1], d2 = hdirs[h * 3 + 2];

  // Q fragments (B-operand): col = c16 (q row), k = kk*32 + g*8 .. +7
  short8 aQ[4];
  float hqp; // hs * qproj(row c16) * log2e
  {
    const short* qr = qbase + (size_t)(q0w + c16) * 3072;
#pragma unroll
    for (int kk = 0; kk < 4; ++kk)
      aQ[kk] = *reinterpret_cast<const short8*>(qr + kk * 32 + g * 8);
    const float hs = head_scales[h];
    hqp = hs * LOG2E * (b2f(qr[0]) * d0 + b2f(qr[1]) * d1 + b2f(qr[2]) * d2);
  }

  float m_s = -1e30f, l_s = 0.0f; // per q-row (= c16), replicated across g
  f32x4 accO[8];
#pragma unroll
  for (int d = 0; d < 8; ++d) {
    f32x4 z = {0.0f, 0.0f, 0.0f, 0.0f};
    accO[d] = z;
  }

  auto stageKV = [&](int buf, int kvt) {
    const int kv0 = kvt * 64;
#pragma unroll
    for (int i = 0; i < 4; ++i) {
      const int s = w * 4 + i;
      {
        const int r = s * 4 + g;            // kv row
        const int c = c16 ^ (r & 7);        // global 16B chunk (16/row)
        const short* ga = kbase + (size_t)(kv0 + r) * 3072 + c * 8;
        __builtin_amdgcn_global_load_lds((const __attribute__((address_space(1))) void*)ga,
                                         (__attribute__((address_space(3))) void*)&Kl[buf][s * 512],
                                         16, 0, 0);
      }
      {
        const int r = s * 8 + (lane >> 3);  // d row
        const int c = (lane & 7) ^ (r & 7); // global 16B chunk (8/row)
        const short* ga = vtb + (size_t)r * 1024 + kv0 + c * 8;
        __builtin_amdgcn_global_load_lds((const __attribute__((address_space(1))) void*)ga,
                                         (__attribute__((address_space(3))) void*)&Vl[buf][s * 512],
                                         16, 0, 0);
      }
    }
    // inline k-projection: 16 lanes/wave compute dot(K[row][0:3], dir)
    if (lane < 16) {
      const short* kr = kbase + (size_t)(kv0 + w * 16 + lane) * 3072;
      kp_lds[buf][w * 16 + lane] = b2f(kr[0]) * d0 + b2f(kr[1]) * d1 + b2f(kr[2]) * d2;
    }
  };

  const int nkv = qt + 1;
  stageKV(0, 0);
  __syncthreads();
  int cur = 0;
  for (int kvt = 0; kvt < nkv; ++kvt) {
    const int kv0 = kvt * 64;
    if (kvt + 1 < nkv) stageKV(cur ^ 1, kvt + 1); // prefetch overlaps compute
    const short* Kc = Kl[cur];
    const short* Vc = Vl[cur];
    const float* kpc = kp_lds[cur];
    const bool diag = (kvt == qt);
    const int nmax = diag ? (w + 1) : 4; // wave-uniform: n-blocks beyond are fully masked

    // ---- swapped QK^T: p[n][j] = P[k = n*16+g*4+j][q = c16] ----
    float p[4][4];
#pragma unroll
    for (int n = 0; n < 4; ++n) {
      if (n >= nmax) {
        p[n][0] = -1e30f; p[n][1] = -1e30f; p[n][2] = -1e30f; p[n][3] = -1e30f;
        continue;
      }
      f32x4 s4 = {0.0f, 0.0f, 0.0f, 0.0f};
      const int r = n * 16 + c16; // kv row within tile (A-operand row)
#pragma unroll
      for (int kk = 0; kk < 4; ++kk) {
        const int cch = (kk * 4 + g) ^ (r & 7);
        short8 bK = *reinterpret_cast<const short8*>(&Kc[r * 128 + cch * 8]);
        s4 = __builtin_amdgcn_mfma_f32_16x16x32_bf16(bK, aQ[kk], s4, 0, 0, 0);
      }
      if (diag) {
#pragma unroll
        for (int j = 0; j < 4; ++j) {
          const int kloc = n * 16 + g * 4 + j;
          const float v = s4[j] * scale2 + hqp * kpc[kloc];
          p[n][j] = (kv0 + kloc <= q_abs) ? v : -1e30f;
        }
      } else {
#pragma unroll
        for (int j = 0; j < 4; ++j) {
          const int kloc = n * 16 + g * 4 + j;
          p[n][j] = s4[j] * scale2 + hqp * kpc[kloc];
        }
      }
    }

    // ---- row max: in-register tree + 2 shfl_xor ----
    float mx;
    {
      float a0 = fmaxf(fmaxf(p[0][0], p[0][1]), fmaxf(p[0][2], p[0][3]));
      float a1 = fmaxf(fmaxf(p[1][0], p[1][1]), fmaxf(p[1][2], p[1][3]));
      float a2 = fmaxf(fmaxf(p[2][0], p[2][1]), fmaxf(p[2][2], p[2][3]));
      float a3 = fmaxf(fmaxf(p[3][0], p[3][1]), fmaxf(p[3][2], p[3][3]));
      mx = fmaxf(fmaxf(a0, a1), fmaxf(a2, a3));
      mx = fmaxf(mx, __shfl_xor(mx, 16, 64));
      mx = fmaxf(mx, __shfl_xor(mx, 32, 64));
    }

    // ---- defer-max (THR = 8 nats = 11.54 in log2 domain) ----
    if (__any(mx - m_s > 11.54f)) {
      const float mn = fmaxf(m_s, mx);
      const float alpha = exp2f(m_s - mn);
      m_s = mn;
      l_s *= alpha;
      float aO[4];
#pragma unroll
      for (int j = 0; j < 4; ++j) aO[j] = __shfl(alpha, g * 4 + j, 64);
#pragma unroll
      for (int d = 0; d < 8; ++d)
#pragma unroll
        for (int j = 0; j < 4; ++j) accO[d][j] *= aO[j];
    }

    // ---- exp2 + row sum (tree + 2 shfl_xor); skipped n-blocks contribute 0 ----
    float s01 = 0.0f, s23 = 0.0f;
#pragma unroll
    for (int n = 0; n < 4; ++n) {
      if (n >= nmax) {
        p[n][0] = 0.0f; p[n][1] = 0.0f; p[n][2] = 0.0f; p[n][3] = 0.0f;
        continue;
      }
      float e0 = exp2f(p[n][0] - m_s), e1 = exp2f(p[n][1] - m_s);
      float e2 = exp2f(p[n][2] - m_s), e3 = exp2f(p[n][3] - m_s);
      p[n][0] = e0; p[n][1] = e1; p[n][2] = e2; p[n][3] = e3;
      if (n < 2) s01 += (e0 + e1) + (e2 + e3); else s23 += (e0 + e1) + (e2 + e3);
    }
    float sum = s01 + s23;
    sum += __shfl_xor(sum, 16, 64);
    sum += __shfl_xor(sum, 32, 64);
    l_s += sum;

    // ---- pack to bf16 pairs: pk[n][u] = {k = n*16+g*4+2u, +1} ----
    uint32_t pk[4][2];
#pragma unroll
    for (int n = 0; n < 4; ++n) {
      pk[n][0] = pack2bf(p[n][0], p[n][1]);
      pk[n][1] = pack2bf(p[n][2], p[n][3]);
    }

    // P columns k >= 32 are all zero iff nmax <= 2 -> skip aPu[1] + PV kk=1
    const int kkmax = (nmax <= 2) ? 1 : 2;

    // ---- redistribute to PV A-fragments: aP[kk] = P[q=c16][k=kk*32+g*8..+7] ----
    union { uint32_t d[4]; short8 s; } aPu[2];
#pragma unroll
    for (int kk = 0; kk < 2; ++kk) {
      if (kk >= kkmax) continue;
#pragma unroll
      for (int wd = 0; wd < 4; ++wd) {
        const int src = (2 * (g & 1) + (wd >> 1)) * 16 + c16;
        const uint32_t v0 = (uint32_t)__shfl((int)pk[kk * 2][wd & 1], src, 64);
        const uint32_t v1 = (uint32_t)__shfl((int)pk[kk * 2 + 1][wd & 1], src, 64);
        aPu[kk].d[wd] = (g >= 2) ? v1 : v0;
      }
    }

    // ---- PV (D row = q = g*4+j, col = d = c16) ----
    if (kkmax == 2) {
#pragma unroll
      for (int dt = 0; dt < 8; ++dt) {
        const int r = dt * 16 + c16; // d row in Vl
        const int c0x = (g) ^ (r & 7);
        const int c1x = (4 + g) ^ (r & 7);
        short8 bV0 = *reinterpret_cast<const short8*>(&Vc[r * 64 + c0x * 8]);
        short8 bV1 = *reinterpret_cast<const short8*>(&Vc[r * 64 + c1x * 8]);
        accO[dt] = __builtin_amdgcn_mfma_f32_16x16x32_bf16(aPu[0].s, bV0, accO[dt], 0, 0, 0);
        accO[dt] = __builtin_amdgcn_mfma_f32_16x16x32_bf16(aPu[1].s, bV1, accO[dt], 0, 0, 0);
      }
    } else {
#pragma unroll
      for (int dt = 0; dt < 8; ++dt) {
        const int r = dt * 16 + c16;
        const int c0x = (g) ^ (r & 7);
        short8 bV0 = *reinterpret_cast<const short8*>(&Vc[r * 64 + c0x * 8]);
        accO[dt] = __builtin_amdgcn_mfma_f32_16x16x32_bf16(aPu[0].s, bV0, accO[dt], 0, 0, 0);
      }
    }
    __syncthreads(); // next buffer staged + all waves done reading cur
    cur ^= 1;
  }

  // ---- epilogue: fetch per-row 1/l via shfl, store bf16 [B,T,D] ----
  float linv[4];
#pragma unroll
  for (int j = 0; j < 4; ++j) linv[j] = 1.0f / __shfl(l_s, g * 4 + j, 64);
#pragma unroll
  for (int j = 0; j < 4; ++j) {
    const size_t rowoff = (size_t)(b * 1024 + q0w + g * 4 + j) * 1024 + h * 128;
#pragma unroll
    for (int dt = 0; dt < 8; ++dt)
      attnb[rowoff + dt * 16 + c16] = f2bf(accO[dt][j] * linv[j]);
  }
}

extern "C" void kernel_launch(void* const* d_in, const int* in_sizes, int n_in,
                              void* d_out, int out_size, void* d_ws, size_t ws_size,
                              hipStream_t stream) {
  const float* x = (const float*)d_in[0];
  const float* Wqkv = (const float*)d_in[1];
  const float* Wout = (const float*)d_in[2];
  const float* hscale = (const float*)d_in[3];
  const float* hdirs = (const float*)d_in[4];
  float* out = (float*)d_out;

  char* ws = (char*)d_ws;
  short* xb = (short*)(ws);                                  // 8 MB (dead after gemm1)
  short* wqkvT = (short*)(ws + (size_t)8 * 1024 * 1024);     // 6 MB
  short* woutT = (short*)(ws + (size_t)14 * 1024 * 1024);    // 2 MB
  short* qkvb = (short*)(ws + (size_t)16 * 1024 * 1024);     // 24 MB
  short* vT = (short*)(ws + (size_t)40 * 1024 * 1024);       // 8 MB
  short* attnb = (short*)(ws + (size_t)48 * 1024 * 1024);    // 8 MB

  prep_kernel<<<6144, 256, 0, stream>>>(x, Wqkv, Wout, xb, wqkvT, woutT);
  gemm_kernel<1><<<dim3(24, 32), 256, 0, stream>>>(xb, wqkvT, (void*)qkvb, 1024, 3072);
  vtrans_kernel<<<1024, 256, 0, stream>>>(qkvb, vT);
  attn_kernel<<<512, 256, 0, stream>>>(qkvb, vT, hscale, hdirs, attnb);
  gemm64_kernel<0><<<dim3(16, 32), 256, 0, stream>>>(attnb, woutT, out, 1024, 1024);
}